// Round 3
// baseline (113.768 us; speedup 1.0000x reference)
//
#include <hip/hip_runtime.h>

typedef unsigned short u16;
typedef __attribute__((ext_vector_type(8))) short short8;
typedef __attribute__((ext_vector_type(4))) float f32x4;

#define SEQ 3072
#define HID 1024
#define HEADS 16
#define HDIM 64
#define SEGLEN 380
#define SEGSTR 381
#define NSEG 8
#define LTOT 3047
#define VPAD 384  // padded per-segment stride in vT (16B-aligned bases)

static __device__ __forceinline__ u16 f2bf(float f) {
  unsigned u = __builtin_bit_cast(unsigned, f);
  u += 0x7fffu + ((u >> 16) & 1u);
  return (u16)(u >> 16);
}
static __device__ __forceinline__ float bf2f(u16 h) {
  unsigned u = ((unsigned)h) << 16;
  return __builtin_bit_cast(float, u);
}

static __device__ __forceinline__ void load_lds16(const void* g, void* l) {
  __builtin_amdgcn_global_load_lds((const __attribute__((address_space(1))) void*)g,
                                   (__attribute__((address_space(3))) void*)l, 16, 0, 0);
}

// ---------------- merged f32 -> bf16 conversion (x4 vectorized) ----------------
__global__ void cvt_all_kernel(const float* __restrict__ x, const float* __restrict__ wq,
                               const float* __restrict__ wk, const float* __restrict__ wv,
                               const float* __restrict__ wo, u16* __restrict__ out) {
  const int i = blockIdx.x * 256 + threadIdx.x;  // float4 index, total 1835008
  const float* s;
  int base;
  if (i < 786432)       { s = x;  base = 0; }
  else if (i < 1048576) { s = wq; base = 786432; }
  else if (i < 1310720) { s = wk; base = 1048576; }
  else if (i < 1572864) { s = wv; base = 1310720; }
  else                  { s = wo; base = 1572864; }
  float4 v = reinterpret_cast<const float4*>(s)[i - base];
  unsigned long long o = (unsigned long long)f2bf(v.x) |
                         ((unsigned long long)f2bf(v.y) << 16) |
                         ((unsigned long long)f2bf(v.z) << 32) |
                         ((unsigned long long)f2bf(v.w) << 48);
  reinterpret_cast<unsigned long long*>(out)[i] = o;
}

// ---------------- GEMM building blocks (tile TM x 64, 4 waves, wave = TM/2 x 32) ----
// LDS row = 32 shorts; physical chunk = logical chunk ^ ((row>>1)&3), both sides.
template <int TM>
static __device__ __forceinline__ void stage_tile(
    const u16* __restrict__ A, const u16* __restrict__ Bw,
    u16* As, u16* Bs, int rowBase, int colBase, int k0) {
  const int tid = threadIdx.x;
  const int w = tid >> 6;
#pragma unroll
  for (int c = 0; c < TM / 64; ++c) {
    const int li = c * 256 + tid;
    const int row = li >> 2;
    const int j = (li & 3) ^ ((row >> 1) & 3);
    load_lds16(A + (size_t)(rowBase + row) * HID + k0 + j * 8, As + (c * 256 + w * 64) * 8);
  }
  {
    const int row = tid >> 2;
    const int j = (tid & 3) ^ ((row >> 1) & 3);
    load_lds16(Bw + (size_t)(colBase + row) * HID + k0 + j * 8, Bs + (w * 64) * 8);
  }
}

template <int TM>
static __device__ __forceinline__ void compute_tile(
    const u16* As, const u16* Bs, int wr, int wc, int lc, int lh, f32x4 (*acc)[2]) {
  constexpr int MF = TM / 32;
  short8 af[MF], bfv[2];
#pragma unroll
  for (int m = 0; m < MF; ++m) {
    const int row = wr + m * 16 + lc;
    af[m] = *reinterpret_cast<const short8*>(As + row * 32 + (lh ^ ((row >> 1) & 3)) * 8);
  }
#pragma unroll
  for (int n = 0; n < 2; ++n) {
    const int row = wc + n * 32 + lc;
    bfv[n] = *reinterpret_cast<const short8*>(Bs + row * 32 + (lh ^ ((row >> 1) & 3)) * 8);
  }
  __builtin_amdgcn_s_setprio(1);
#pragma unroll
  for (int m = 0; m < MF; ++m)
#pragma unroll
    for (int n = 0; n < 2; ++n)
      acc[m][n] = __builtin_amdgcn_mfma_f32_16x16x32_bf16(af[m], bfv[n], acc[m][n], 0, 0, 0);
  __builtin_amdgcn_s_setprio(0);
}

#define BAR() __builtin_amdgcn_s_barrier()

template <int TM>
static __device__ __forceinline__ void wait_steady() {
  if constexpr (TM == 128) asm volatile("s_waitcnt vmcnt(6)" ::: "memory");
  else                     asm volatile("s_waitcnt vmcnt(4)" ::: "memory");
}
template <int TM>
static __device__ __forceinline__ void wait_tail1() {
  if constexpr (TM == 128) asm volatile("s_waitcnt vmcnt(3)" ::: "memory");
  else                     asm volatile("s_waitcnt vmcnt(2)" ::: "memory");
}
static __device__ __forceinline__ void wait_zero() {
  asm volatile("s_waitcnt vmcnt(0)" ::: "memory");
}

// triple-buffered depth-2 pipelined mainloop over K=1024, BK=32 (32 tiles)
template <int TM>
static __device__ __forceinline__ void gemm_mainloop(
    const u16* __restrict__ A, const u16* __restrict__ Bw,
    u16* As0, u16* Bs0, u16* As1, u16* Bs1, u16* As2, u16* Bs2,
    int rowBase, int colBase, int wr, int wc, int lc, int lh, f32x4 (*acc)[2]) {
  stage_tile<TM>(A, Bw, As0, Bs0, rowBase, colBase, 0);
  stage_tile<TM>(A, Bw, As1, Bs1, rowBase, colBase, 32);
#pragma unroll 1
  for (int t = 0; t < 30; t += 3) {
    stage_tile<TM>(A, Bw, As2, Bs2, rowBase, colBase, (t + 2) * 32);
    wait_steady<TM>(); BAR();
    compute_tile<TM>(As0, Bs0, wr, wc, lc, lh, acc);
    BAR();
    stage_tile<TM>(A, Bw, As0, Bs0, rowBase, colBase, (t + 3) * 32);
    wait_steady<TM>(); BAR();
    compute_tile<TM>(As1, Bs1, wr, wc, lc, lh, acc);
    BAR();
    stage_tile<TM>(A, Bw, As1, Bs1, rowBase, colBase, (t + 4) * 32);
    wait_steady<TM>(); BAR();
    compute_tile<TM>(As2, Bs2, wr, wc, lc, lh, acc);
    BAR();
  }
  // tiles 30 (buf0) and 31 (buf1) already staged
  wait_tail1<TM>(); BAR();
  compute_tile<TM>(As0, Bs0, wr, wc, lc, lh, acc);
  BAR();
  wait_zero(); BAR();
  compute_tile<TM>(As1, Bs1, wr, wc, lc, lh, acc);
}

// ---------------- fused QKV projection + RoPE ----------------
// grid: (SEQ/128, 48); blockIdx.y: /16 -> {q,k,v}, &15 -> 64-col tile
__global__ __launch_bounds__(256) void qkv_gemm_kernel(
    const u16* __restrict__ xb,
    const u16* __restrict__ wqb, const u16* __restrict__ wkb, const u16* __restrict__ wvb,
    const float* __restrict__ bq, const float* __restrict__ bk, const float* __restrict__ bv,
    u16* __restrict__ qb, u16* __restrict__ kbuf, u16* __restrict__ vT) {
  __shared__ u16 As[3][128 * 32];
  __shared__ u16 Bs[3][64 * 32];
  const int which = blockIdx.y >> 4;
  const u16* Bw = (which == 0) ? wqb : (which == 1) ? wkb : wvb;
  const float* bias = (which == 0) ? bq : (which == 1) ? bk : bv;
  const int rowBase = blockIdx.x * 128;
  const int colBase = (blockIdx.y & 15) * 64;
  const int tid = threadIdx.x;
  const int w = tid >> 6, l = tid & 63, lc = l & 15, lh = l >> 4;
  const int wr = (w >> 1) * 64, wc = (w & 1) * 16;

  f32x4 acc[4][2];
  f32x4 z4 = {0.f, 0.f, 0.f, 0.f};
#pragma unroll
  for (int m = 0; m < 4; ++m) { acc[m][0] = z4; acc[m][1] = z4; }

  gemm_mainloop<128>(xb, Bw, As[0], Bs[0], As[1], Bs[1], As[2], Bs[2],
                     rowBase, colBase, wr, wc, lc, lh, acc);

  const int f = wc + lc;                 // in [0,32): rotation index
  const int col0 = colBase + f;
  if (which < 2) {
    u16* outp = which ? kbuf : qb;
    const float bv0 = bias[col0];
    const float bv1 = bias[col0 + 32];
    const float invf = exp2f(-(float)f * 0.10381025296523007f);  // 10^(-f/32)
#pragma unroll
    for (int m = 0; m < 4; ++m) {
      const int row0 = rowBase + wr + m * 16 + lh * 4;
#pragma unroll
      for (int r = 0; r < 4; ++r) {
        const int row = row0 + r;
        const int rr = row % SEGSTR;
        const float pos = (float)((rr < SEGLEN) ? rr : 0);
        float sn, cs;
        sincosf(pos * invf, &sn, &cs);
        const float t1 = acc[m][0][r] + bv0;
        const float t2 = acc[m][1][r] + bv1;
        const size_t base = (size_t)row * HID + col0;
        outp[base] = f2bf(t1 * cs - t2 * sn);
        outp[base + 32] = f2bf(t1 * sn + t2 * cs);
      }
    }
  } else {
#pragma unroll
    for (int n = 0; n < 2; ++n) {
      const int col = col0 + n * 32;
      const float bvl = bias[col];
#pragma unroll
      for (int m = 0; m < 4; ++m) {
        const int row0 = rowBase + wr + m * 16 + lh * 4;
#pragma unroll
        for (int r = 0; r < 4; ++r) {
          const float v = acc[m][n][r] + bvl;
          const int row = row0 + r;
          const int sg = row / SEGSTR;
          const int j = row - sg * SEGSTR;
          if (sg < NSEG)
            vT[(size_t)col * (NSEG * VPAD) + sg * VPAD + j] = f2bf(v);
        }
      }
    }
  }
}

// ---------------- output projection (f32 out), tile 64x64 ----------------
__global__ __launch_bounds__(256) void out_gemm_kernel(
    const u16* __restrict__ aob, const u16* __restrict__ wob,
    const float* __restrict__ bo, float* __restrict__ out) {
  __shared__ u16 As[3][64 * 32];
  __shared__ u16 Bs[3][64 * 32];
  const int rowBase = blockIdx.x * 64;
  const int colBase = blockIdx.y * 64;
  const int tid = threadIdx.x;
  const int w = tid >> 6, l = tid & 63, lc = l & 15, lh = l >> 4;
  const int wr = (w >> 1) * 32, wc = (w & 1) * 16;
  f32x4 acc[2][2];
  f32x4 z4 = {0.f, 0.f, 0.f, 0.f};
#pragma unroll
  for (int m = 0; m < 2; ++m) { acc[m][0] = z4; acc[m][1] = z4; }

  gemm_mainloop<64>(aob, wob, As[0], Bs[0], As[1], Bs[1], As[2], Bs[2],
                    rowBase, colBase, wr, wc, lc, lh, acc);

#pragma unroll
  for (int n = 0; n < 2; ++n) {
    const int col = colBase + wc + n * 32 + lc;
    const float bvl = bo[col];
#pragma unroll
    for (int m = 0; m < 2; ++m) {
      const int row0 = rowBase + wr + m * 16 + lh * 4;
#pragma unroll
      for (int r = 0; r < 4; ++r)
        out[(size_t)(row0 + r) * HID + col] = acc[m][n][r] + bvl;
    }
  }
}

// ---------------- block-diagonal flash attention ----------------
// grid: (6 qtiles, 8 segs, 16 heads), 256 threads = 4 waves x 16 q-rows
__global__ __launch_bounds__(256) void attn_kernel(
    const u16* __restrict__ qb, const u16* __restrict__ kb,
    const u16* __restrict__ vT, u16* __restrict__ ao) {
  __shared__ u16 P_lds[4][16 * 32];
  const int tid = threadIdx.x;
  const int w = tid >> 6, l = tid & 63, lc = l & 15, lh = l >> 4;
  const int qtile = blockIdx.x;
  const int seg = blockIdx.y;
  const int h = blockIdx.z;
  const int segbase = seg * SEGSTR;
  const int rloc = qtile * 64 + w * 16;

  const u16* qrow = qb + (size_t)(segbase + rloc + lc) * HID + h * HDIM + lh * 8;
  const short8 qf0 = *reinterpret_cast<const short8*>(qrow);
  const short8 qf1 = *reinterpret_cast<const short8*>(qrow + 32);

  f32x4 z4 = {0.f, 0.f, 0.f, 0.f};
  f32x4 accO[4];
  float m_run[4], psum[4];
#pragma unroll
  for (int n = 0; n < 4; ++n) accO[n] = z4;
#pragma unroll
  for (int r = 0; r < 4; ++r) { m_run[r] = -1e30f; psum[r] = 0.f; }

  for (int kb0 = 0; kb0 < SEGLEN; kb0 += 32) {
    const u16* krow = kb + (size_t)(segbase + kb0 + lc) * HID + h * HDIM + lh * 8;
    const short8 kf00 = *reinterpret_cast<const short8*>(krow);
    const short8 kf01 = *reinterpret_cast<const short8*>(krow + 32);
    const short8 kf10 = *reinterpret_cast<const short8*>(krow + 16 * HID);
    const short8 kf11 = *reinterpret_cast<const short8*>(krow + 16 * HID + 32);
    f32x4 s0 = z4, s1 = z4;
    __builtin_amdgcn_s_setprio(1);
    s0 = __builtin_amdgcn_mfma_f32_16x16x32_bf16(qf0, kf00, s0, 0, 0, 0);
    s0 = __builtin_amdgcn_mfma_f32_16x16x32_bf16(qf1, kf01, s0, 0, 0, 0);
    s1 = __builtin_amdgcn_mfma_f32_16x16x32_bf16(qf0, kf10, s1, 0, 0, 0);
    s1 = __builtin_amdgcn_mfma_f32_16x16x32_bf16(qf1, kf11, s1, 0, 0, 0);
    __builtin_amdgcn_s_setprio(0);

    const bool v0 = (kb0 + lc) < SEGLEN;
    const bool v1 = (kb0 + 16 + lc) < SEGLEN;
    float p0[4], p1[4];
#pragma unroll
    for (int r = 0; r < 4; ++r) {
      float a = v0 ? s0[r] * 0.125f : -1e30f;
      float b = v1 ? s1[r] * 0.125f : -1e30f;
      float mx = fmaxf(a, b);
      mx = fmaxf(mx, __shfl_xor(mx, 1));
      mx = fmaxf(mx, __shfl_xor(mx, 2));
      mx = fmaxf(mx, __shfl_xor(mx, 4));
      mx = fmaxf(mx, __shfl_xor(mx, 8));
      const float mnew = fmaxf(m_run[r], mx);
      const float sc = __expf(m_run[r] - mnew);
      p0[r] = __expf(a - mnew);
      p1[r] = __expf(b - mnew);
      psum[r] = psum[r] * sc + p0[r] + p1[r];
      m_run[r] = mnew;
      accO[0][r] *= sc; accO[1][r] *= sc; accO[2][r] *= sc; accO[3][r] *= sc;
    }
    // P bounce through LDS with chunk swizzle: physical chunk = c ^ ((row>>1)&3)
    u16* pl = &P_lds[w][0];
#pragma unroll
    for (int r = 0; r < 4; ++r) {
      const int prow = lh * 4 + r;
      const int sw = ((prow >> 1) & 3);
      const int c0 = (lc >> 3) ^ sw;
      const int c1 = ((16 + lc) >> 3) ^ sw;
      pl[prow * 32 + c0 * 8 + (lc & 7)] = f2bf(p0[r]);
      pl[prow * 32 + c1 * 8 + (lc & 7)] = f2bf(p1[r]);
    }
    const int pcp = lh ^ ((lc >> 1) & 3);
    const short8 pf = *reinterpret_cast<const short8*>(&pl[lc * 32 + pcp * 8]);

    const u16* vbase = vT + (size_t)seg * VPAD + kb0 + lh * 8;
    __builtin_amdgcn_s_setprio(1);
#pragma unroll
    for (int n = 0; n < 4; ++n) {
      const short8 vf = *reinterpret_cast<const short8*>(
          vbase + (size_t)(h * HDIM + n * 16 + lc) * (NSEG * VPAD));
      accO[n] = __builtin_amdgcn_mfma_f32_16x16x32_bf16(pf, vf, accO[n], 0, 0, 0);
    }
    __builtin_amdgcn_s_setprio(0);
  }

#pragma unroll
  for (int r = 0; r < 4; ++r) {
    float s = psum[r];
    s += __shfl_xor(s, 1);
    s += __shfl_xor(s, 2);
    s += __shfl_xor(s, 4);
    s += __shfl_xor(s, 8);
    psum[r] = 1.0f / s;
  }
#pragma unroll
  for (int r = 0; r < 4; ++r) {
    const int lrow = rloc + lh * 4 + r;
    if (lrow < SEGLEN) {
      const size_t orow = (size_t)(segbase + lrow) * HID + h * HDIM;
#pragma unroll
      for (int n = 0; n < 4; ++n)
        ao[orow + n * 16 + lc] = f2bf(accO[n][r] * psum[r]);
    }
  }
}

// ---------------- separator + pad-row fixup ----------------
__global__ void fixup_kernel(const u16* __restrict__ vT, u16* __restrict__ ao) {
  int idx = blockIdx.x * 256 + threadIdx.x;  // 32*1024 threads
  int r = idx >> 10, c = idx & 1023;
  if (r < NSEG - 1) {
    int row = r * SEGSTR + SEGLEN;
    ao[(size_t)row * HID + c] = vT[(size_t)c * (NSEG * VPAD) + r * VPAD + SEGLEN];
  } else {
    int row = LTOT + (r - (NSEG - 1));
    ao[(size_t)row * HID + c] = 0;
  }
}

extern "C" void kernel_launch(void* const* d_in, const int* in_sizes, int n_in,
                              void* d_out, int out_size, void* d_ws, size_t ws_size,
                              hipStream_t stream) {
  const float* x  = (const float*)d_in[0];
  const float* wq = (const float*)d_in[1];
  const float* bq = (const float*)d_in[2];
  const float* wk = (const float*)d_in[3];
  const float* bk = (const float*)d_in[4];
  const float* wv = (const float*)d_in[5];
  const float* bv = (const float*)d_in[6];
  const float* wo = (const float*)d_in[7];
  const float* bo = (const float*)d_in[8];
  float* out = (float*)d_out;

  u16* ws = (u16*)d_ws;
  u16* xb   = ws;                    // SEQ*HID
  u16* wqb  = xb  + (size_t)SEQ * HID;
  u16* wkb  = wqb + (size_t)HID * HID;
  u16* wvb  = wkb + (size_t)HID * HID;
  u16* wob  = wvb + (size_t)HID * HID;
  u16* qb   = wob + (size_t)HID * HID;
  u16* kbuf = qb  + (size_t)SEQ * HID;
  u16* vT   = kbuf + (size_t)SEQ * HID;  // [HID][NSEG*VPAD]
  u16* aob  = vT  + (size_t)HID * (NSEG * VPAD);

  cvt_all_kernel<<<7168, 256, 0, stream>>>(x, wq, wk, wv, wo, ws);

  qkv_gemm_kernel<<<dim3(SEQ / 128, 48), 256, 0, stream>>>(
      xb, wqb, wkb, wvb, bq, bk, bv, qb, kbuf, vT);

  attn_kernel<<<dim3(6, NSEG, HEADS), 256, 0, stream>>>(qb, kbuf, vT, aob);

  fixup_kernel<<<32 * 1024 / 256, 256, 0, stream>>>(vT, aob);

  out_gemm_kernel<<<dim3(SEQ / 64, HID / 64), 256, 0, stream>>>(aob, wob, bo, out);

  (void)in_sizes; (void)n_in; (void)out_size; (void)ws_size;
}

// Round 4
// 102.149 us; speedup vs baseline: 1.1137x; 1.1137x over previous
//
#include <hip/hip_runtime.h>

typedef unsigned short u16;
typedef __attribute__((ext_vector_type(8))) short short8;
typedef __attribute__((ext_vector_type(4))) float f32x4;

#define SEQ 3072
#define HID 1024
#define HEADS 16
#define HDIM 64
#define SEGLEN 380
#define SEGSTR 381
#define NSEG 8
#define LTOT 3047
#define VPAD 384  // padded per-segment stride in vT (16B-aligned bases)

static __device__ __forceinline__ u16 f2bf(float f) {
  unsigned u = __builtin_bit_cast(unsigned, f);
  u += 0x7fffu + ((u >> 16) & 1u);
  return (u16)(u >> 16);
}
static __device__ __forceinline__ float bf2f(u16 h) {
  unsigned u = ((unsigned)h) << 16;
  return __builtin_bit_cast(float, u);
}

static __device__ __forceinline__ void load_lds16(const void* g, void* l) {
  __builtin_amdgcn_global_load_lds((const __attribute__((address_space(1))) void*)g,
                                   (__attribute__((address_space(3))) void*)l, 16, 0, 0);
}

#define BAR() __builtin_amdgcn_s_barrier()
#define VM(N) asm volatile("s_waitcnt vmcnt(" #N ")" ::: "memory")

// ---------------- merged f32 -> bf16 conversion (x4 vectorized) ----------------
__global__ void cvt_all_kernel(const float* __restrict__ x, const float* __restrict__ wq,
                               const float* __restrict__ wk, const float* __restrict__ wv,
                               const float* __restrict__ wo, u16* __restrict__ out) {
  const int i = blockIdx.x * 256 + threadIdx.x;  // float4 index, total 1835008
  const float* s;
  int base;
  if (i < 786432)       { s = x;  base = 0; }
  else if (i < 1048576) { s = wq; base = 786432; }
  else if (i < 1310720) { s = wk; base = 1048576; }
  else if (i < 1572864) { s = wv; base = 1310720; }
  else                  { s = wo; base = 1572864; }
  float4 v = reinterpret_cast<const float4*>(s)[i - base];
  unsigned long long o = (unsigned long long)f2bf(v.x) |
                         ((unsigned long long)f2bf(v.y) << 16) |
                         ((unsigned long long)f2bf(v.z) << 32) |
                         ((unsigned long long)f2bf(v.w) << 48);
  reinterpret_cast<unsigned long long*>(out)[i] = o;
}

// ================= QKV GEMM: 128x128 tile, 512 threads (8 waves), BK=32 =========
// LDS row = 32 shorts (64B); physical chunk = logical ^ ((row>>1)&3), both sides.
static __device__ __forceinline__ void stage_qkv(
    const u16* __restrict__ A, const u16* __restrict__ Bw,
    u16* As, u16* Bs, int rowBase, int colBase, int k0) {
  const int tid = threadIdx.x;
  const int w = tid >> 6;
  const int row = tid >> 2;
  const int j = (tid & 3) ^ ((row >> 1) & 3);
  load_lds16(A + (size_t)(rowBase + row) * HID + k0 + j * 8, As + (w * 64) * 8);
  load_lds16(Bw + (size_t)(colBase + row) * HID + k0 + j * 8, Bs + (w * 64) * 8);
}

// wave w: rows wr=(w>>2)*64 (4 m-frags); cols cb0=(c2>>1)*64+(c2&1)*16 and cb0+32
static __device__ __forceinline__ void compute_qkv(
    const u16* As, const u16* Bs, int wr, int cb0, int lc, int lh, f32x4 (*acc)[2]) {
  short8 af[4], bfv[2];
#pragma unroll
  for (int m = 0; m < 4; ++m) {
    const int row = wr + m * 16 + lc;
    af[m] = *reinterpret_cast<const short8*>(As + row * 32 + (lh ^ ((row >> 1) & 3)) * 8);
  }
#pragma unroll
  for (int n = 0; n < 2; ++n) {
    const int row = cb0 + n * 32 + lc;
    bfv[n] = *reinterpret_cast<const short8*>(Bs + row * 32 + (lh ^ ((row >> 1) & 3)) * 8);
  }
  __builtin_amdgcn_s_setprio(1);
#pragma unroll
  for (int m = 0; m < 4; ++m)
#pragma unroll
    for (int n = 0; n < 2; ++n)
      acc[m][n] = __builtin_amdgcn_mfma_f32_16x16x32_bf16(af[m], bfv[n], acc[m][n], 0, 0, 0);
  __builtin_amdgcn_s_setprio(0);
}

// grid: (SEQ/128, 24); blockIdx.y: /8 -> {q,k,v}, &7 -> 128-col tile
__global__ __launch_bounds__(512) void qkv_gemm_kernel(
    const u16* __restrict__ xb,
    const u16* __restrict__ wqb, const u16* __restrict__ wkb, const u16* __restrict__ wvb,
    const float* __restrict__ bq, const float* __restrict__ bk, const float* __restrict__ bv,
    u16* __restrict__ qb, u16* __restrict__ kbuf, u16* __restrict__ vT) {
  __shared__ u16 As[3][128 * 32];
  __shared__ u16 Bs[3][128 * 32];
  const int which = blockIdx.y >> 3;
  const u16* Bw = (which == 0) ? wqb : (which == 1) ? wkb : wvb;
  const float* bias = (which == 0) ? bq : (which == 1) ? bk : bv;
  const int rowBase = blockIdx.x * 128;
  const int colBase = (blockIdx.y & 7) * 128;
  const int tid = threadIdx.x;
  const int w = tid >> 6, l = tid & 63, lc = l & 15, lh = l >> 4;
  const int wr = (w >> 2) * 64;
  const int c2 = w & 3;
  const int cb0 = (c2 >> 1) * 64 + (c2 & 1) * 16;

  f32x4 acc[4][2];
  f32x4 z4 = {0.f, 0.f, 0.f, 0.f};
#pragma unroll
  for (int m = 0; m < 4; ++m) { acc[m][0] = z4; acc[m][1] = z4; }

  stage_qkv(xb, Bw, As[0], Bs[0], rowBase, colBase, 0);
  stage_qkv(xb, Bw, As[1], Bs[1], rowBase, colBase, 32);
#pragma unroll 1
  for (int t = 0; t < 30; t += 3) {
    stage_qkv(xb, Bw, As[2], Bs[2], rowBase, colBase, (t + 2) * 32);
    VM(4); BAR();
    compute_qkv(As[0], Bs[0], wr, cb0, lc, lh, acc);
    BAR();
    stage_qkv(xb, Bw, As[0], Bs[0], rowBase, colBase, (t + 3) * 32);
    VM(4); BAR();
    compute_qkv(As[1], Bs[1], wr, cb0, lc, lh, acc);
    BAR();
    stage_qkv(xb, Bw, As[1], Bs[1], rowBase, colBase, (t + 4) * 32);
    VM(4); BAR();
    compute_qkv(As[2], Bs[2], wr, cb0, lc, lh, acc);
    BAR();
  }
  VM(2); BAR();
  compute_qkv(As[0], Bs[0], wr, cb0, lc, lh, acc);  // tile 30
  BAR();
  VM(0); BAR();
  compute_qkv(As[1], Bs[1], wr, cb0, lc, lh, acc);  // tile 31

  // epilogue: thread holds cols (col0, col0+32) -> RoPE pair is local
  const int f = (c2 & 1) * 16 + lc;  // [0,32)
  const int col0 = colBase + (c2 >> 1) * 64 + f;
  if (which < 2) {
    u16* outp = which ? kbuf : qb;
    const float bv0 = bias[col0];
    const float bv1 = bias[col0 + 32];
    const float invf = exp2f(-(float)f * 0.10381025296523007f);  // 10^(-f/32)
#pragma unroll
    for (int m = 0; m < 4; ++m) {
      const int row0 = rowBase + wr + m * 16 + lh * 4;
#pragma unroll
      for (int r = 0; r < 4; ++r) {
        const int row = row0 + r;
        const int rr = row % SEGSTR;
        const float pos = (float)((rr < SEGLEN) ? rr : 0);
        float sn, cs;
        sincosf(pos * invf, &sn, &cs);
        const float t1 = acc[m][0][r] + bv0;
        const float t2 = acc[m][1][r] + bv1;
        const size_t base = (size_t)row * HID + col0;
        outp[base] = f2bf(t1 * cs - t2 * sn);
        outp[base + 32] = f2bf(t1 * sn + t2 * cs);
      }
    }
  } else {
#pragma unroll
    for (int n = 0; n < 2; ++n) {
      const int col = col0 + n * 32;
      const float bvl = bias[col];
#pragma unroll
      for (int m = 0; m < 4; ++m) {
        const int row0 = rowBase + wr + m * 16 + lh * 4;
#pragma unroll
        for (int r = 0; r < 4; ++r) {
          const float v = acc[m][n][r] + bvl;
          const int row = row0 + r;
          const int sg = row / SEGSTR;
          const int j = row - sg * SEGSTR;
          if (sg < NSEG)
            vT[(size_t)col * (NSEG * VPAD) + sg * VPAD + j] = f2bf(v);
        }
      }
    }
  }
}

// ================= OUT GEMM: 128x64 tile, 512 threads (8 waves), BK=64 =========
// LDS row = 64 shorts (128B); physical chunk = logical ^ (row&7), both sides.
static __device__ __forceinline__ void stage_out(
    const u16* __restrict__ A, const u16* __restrict__ Bw,
    u16* As, u16* Bs, int rowBase, int colBase, int k0) {
  const int tid = threadIdx.x;
  const int w = tid >> 6;
#pragma unroll
  for (int c = 0; c < 2; ++c) {
    const int li = c * 512 + tid;
    const int row = li >> 3;
    const int j = (li & 7) ^ (row & 7);
    load_lds16(A + (size_t)(rowBase + row) * HID + k0 + j * 8,
               As + (c * 512 + w * 64) * 8);
  }
  {
    const int row = tid >> 3;
    const int j = (tid & 7) ^ (row & 7);
    load_lds16(Bw + (size_t)(colBase + row) * HID + k0 + j * 8, Bs + (w * 64) * 8);
  }
}

// wave w: rows wrO=(w>>1)*32 (2 m-frags), cols wcO=(w&1)*32 (2 n-frags), 2 k-subs
static __device__ __forceinline__ void compute_out(
    const u16* As, const u16* Bs, int wrO, int wcO, int lc, int lh, f32x4 (*acc)[2]) {
  short8 af[2][2], bfv[2][2];
#pragma unroll
  for (int m = 0; m < 2; ++m) {
    const int row = wrO + m * 16 + lc;
#pragma unroll
    for (int ks = 0; ks < 2; ++ks)
      af[m][ks] = *reinterpret_cast<const short8*>(
          As + row * 64 + (((ks * 4 + lh) ^ (row & 7))) * 8);
  }
#pragma unroll
  for (int n = 0; n < 2; ++n) {
    const int row = wcO + n * 16 + lc;
#pragma unroll
    for (int ks = 0; ks < 2; ++ks)
      bfv[n][ks] = *reinterpret_cast<const short8*>(
          Bs + row * 64 + (((ks * 4 + lh) ^ (row & 7))) * 8);
  }
  __builtin_amdgcn_s_setprio(1);
#pragma unroll
  for (int ks = 0; ks < 2; ++ks)
#pragma unroll
    for (int m = 0; m < 2; ++m)
#pragma unroll
      for (int n = 0; n < 2; ++n)
        acc[m][n] = __builtin_amdgcn_mfma_f32_16x16x32_bf16(af[m][ks], bfv[n][ks], acc[m][n], 0, 0, 0);
  __builtin_amdgcn_s_setprio(0);
}

// grid: (SEQ/128, HID/64), 512 threads
__global__ __launch_bounds__(512) void out_gemm_kernel(
    const u16* __restrict__ aob, const u16* __restrict__ wob,
    const float* __restrict__ bo, float* __restrict__ out) {
  __shared__ u16 As[3][128 * 64];
  __shared__ u16 Bs[3][64 * 64];
  const int rowBase = blockIdx.x * 128;
  const int colBase = blockIdx.y * 64;
  const int tid = threadIdx.x;
  const int w = tid >> 6, l = tid & 63, lc = l & 15, lh = l >> 4;
  const int wrO = (w >> 1) * 32, wcO = (w & 1) * 32;
  f32x4 acc[2][2];
  f32x4 z4 = {0.f, 0.f, 0.f, 0.f};
#pragma unroll
  for (int m = 0; m < 2; ++m) { acc[m][0] = z4; acc[m][1] = z4; }

  stage_out(aob, wob, As[0], Bs[0], rowBase, colBase, 0);
  stage_out(aob, wob, As[1], Bs[1], rowBase, colBase, 64);
#pragma unroll 1
  for (int t = 0; t < 12; t += 3) {
    stage_out(aob, wob, As[2], Bs[2], rowBase, colBase, (t + 2) * 64);
    VM(6); BAR();
    compute_out(As[0], Bs[0], wrO, wcO, lc, lh, acc);
    BAR();
    stage_out(aob, wob, As[0], Bs[0], rowBase, colBase, (t + 3) * 64);
    VM(6); BAR();
    compute_out(As[1], Bs[1], wrO, wcO, lc, lh, acc);
    BAR();
    stage_out(aob, wob, As[1], Bs[1], rowBase, colBase, (t + 4) * 64);
    VM(6); BAR();
    compute_out(As[2], Bs[2], wrO, wcO, lc, lh, acc);
    BAR();
  }
  // computed 0..11, staged 0..13
  stage_out(aob, wob, As[2], Bs[2], rowBase, colBase, 14 * 64);
  VM(6); BAR();
  compute_out(As[0], Bs[0], wrO, wcO, lc, lh, acc);  // 12
  BAR();
  stage_out(aob, wob, As[0], Bs[0], rowBase, colBase, 15 * 64);
  VM(6); BAR();
  compute_out(As[1], Bs[1], wrO, wcO, lc, lh, acc);  // 13
  BAR();
  VM(3); BAR();
  compute_out(As[2], Bs[2], wrO, wcO, lc, lh, acc);  // 14
  BAR();
  VM(0); BAR();
  compute_out(As[0], Bs[0], wrO, wcO, lc, lh, acc);  // 15

#pragma unroll
  for (int n = 0; n < 2; ++n) {
    const int col = colBase + wcO + n * 16 + lc;
    const float bvl = bo[col];
#pragma unroll
    for (int m = 0; m < 2; ++m) {
      const int row0 = rowBase + wrO + m * 16 + lh * 4;
#pragma unroll
      for (int r = 0; r < 4; ++r)
        out[(size_t)(row0 + r) * HID + col] = acc[m][n][r] + bvl;
    }
  }
}

// ---------------- block-diagonal flash attention ----------------
// grid: (6 qtiles, 8 segs, 16 heads), 256 threads = 4 waves x 16 q-rows
__global__ __launch_bounds__(256) void attn_kernel(
    const u16* __restrict__ qb, const u16* __restrict__ kb,
    const u16* __restrict__ vT, u16* __restrict__ ao) {
  __shared__ u16 P_lds[4][16 * 32];
  const int tid = threadIdx.x;
  const int w = tid >> 6, l = tid & 63, lc = l & 15, lh = l >> 4;
  const int qtile = blockIdx.x;
  const int seg = blockIdx.y;
  const int h = blockIdx.z;
  const int segbase = seg * SEGSTR;
  const int rloc = qtile * 64 + w * 16;

  const u16* qrow = qb + (size_t)(segbase + rloc + lc) * HID + h * HDIM + lh * 8;
  const short8 qf0 = *reinterpret_cast<const short8*>(qrow);
  const short8 qf1 = *reinterpret_cast<const short8*>(qrow + 32);

  f32x4 z4 = {0.f, 0.f, 0.f, 0.f};
  f32x4 accO[4];
  float m_run[4], psum[4];
#pragma unroll
  for (int n = 0; n < 4; ++n) accO[n] = z4;
#pragma unroll
  for (int r = 0; r < 4; ++r) { m_run[r] = -1e30f; psum[r] = 0.f; }

  for (int kb0 = 0; kb0 < SEGLEN; kb0 += 32) {
    const u16* krow = kb + (size_t)(segbase + kb0 + lc) * HID + h * HDIM + lh * 8;
    const short8 kf00 = *reinterpret_cast<const short8*>(krow);
    const short8 kf01 = *reinterpret_cast<const short8*>(krow + 32);
    const short8 kf10 = *reinterpret_cast<const short8*>(krow + 16 * HID);
    const short8 kf11 = *reinterpret_cast<const short8*>(krow + 16 * HID + 32);
    f32x4 s0 = z4, s1 = z4;
    __builtin_amdgcn_s_setprio(1);
    s0 = __builtin_amdgcn_mfma_f32_16x16x32_bf16(qf0, kf00, s0, 0, 0, 0);
    s0 = __builtin_amdgcn_mfma_f32_16x16x32_bf16(qf1, kf01, s0, 0, 0, 0);
    s1 = __builtin_amdgcn_mfma_f32_16x16x32_bf16(qf0, kf10, s1, 0, 0, 0);
    s1 = __builtin_amdgcn_mfma_f32_16x16x32_bf16(qf1, kf11, s1, 0, 0, 0);
    __builtin_amdgcn_s_setprio(0);

    const bool v0 = (kb0 + lc) < SEGLEN;
    const bool v1 = (kb0 + 16 + lc) < SEGLEN;
    float p0[4], p1[4];
#pragma unroll
    for (int r = 0; r < 4; ++r) {
      float a = v0 ? s0[r] * 0.125f : -1e30f;
      float b = v1 ? s1[r] * 0.125f : -1e30f;
      float mx = fmaxf(a, b);
      mx = fmaxf(mx, __shfl_xor(mx, 1));
      mx = fmaxf(mx, __shfl_xor(mx, 2));
      mx = fmaxf(mx, __shfl_xor(mx, 4));
      mx = fmaxf(mx, __shfl_xor(mx, 8));
      const float mnew = fmaxf(m_run[r], mx);
      const float sc = __expf(m_run[r] - mnew);
      p0[r] = __expf(a - mnew);
      p1[r] = __expf(b - mnew);
      psum[r] = psum[r] * sc + p0[r] + p1[r];
      m_run[r] = mnew;
      accO[0][r] *= sc; accO[1][r] *= sc; accO[2][r] *= sc; accO[3][r] *= sc;
    }
    // P bounce through LDS with chunk swizzle: physical chunk = c ^ ((row>>1)&3)
    u16* pl = &P_lds[w][0];
#pragma unroll
    for (int r = 0; r < 4; ++r) {
      const int prow = lh * 4 + r;
      const int sw = ((prow >> 1) & 3);
      const int c0 = (lc >> 3) ^ sw;
      const int c1 = ((16 + lc) >> 3) ^ sw;
      pl[prow * 32 + c0 * 8 + (lc & 7)] = f2bf(p0[r]);
      pl[prow * 32 + c1 * 8 + (lc & 7)] = f2bf(p1[r]);
    }
    const int pcp = lh ^ ((lc >> 1) & 3);
    const short8 pf = *reinterpret_cast<const short8*>(&pl[lc * 32 + pcp * 8]);

    const u16* vbase = vT + (size_t)seg * VPAD + kb0 + lh * 8;
    __builtin_amdgcn_s_setprio(1);
#pragma unroll
    for (int n = 0; n < 4; ++n) {
      const short8 vf = *reinterpret_cast<const short8*>(
          vbase + (size_t)(h * HDIM + n * 16 + lc) * (NSEG * VPAD));
      accO[n] = __builtin_amdgcn_mfma_f32_16x16x32_bf16(pf, vf, accO[n], 0, 0, 0);
    }
    __builtin_amdgcn_s_setprio(0);
  }

#pragma unroll
  for (int r = 0; r < 4; ++r) {
    float s = psum[r];
    s += __shfl_xor(s, 1);
    s += __shfl_xor(s, 2);
    s += __shfl_xor(s, 4);
    s += __shfl_xor(s, 8);
    psum[r] = 1.0f / s;
  }
#pragma unroll
  for (int r = 0; r < 4; ++r) {
    const int lrow = rloc + lh * 4 + r;
    if (lrow < SEGLEN) {
      const size_t orow = (size_t)(segbase + lrow) * HID + h * HDIM;
#pragma unroll
      for (int n = 0; n < 4; ++n)
        ao[orow + n * 16 + lc] = f2bf(accO[n][r] * psum[r]);
    }
  }
}

// ---------------- separator + pad-row fixup ----------------
__global__ void fixup_kernel(const u16* __restrict__ vT, u16* __restrict__ ao) {
  int idx = blockIdx.x * 256 + threadIdx.x;  // 32*1024 threads
  int r = idx >> 10, c = idx & 1023;
  if (r < NSEG - 1) {
    int row = r * SEGSTR + SEGLEN;
    ao[(size_t)row * HID + c] = vT[(size_t)c * (NSEG * VPAD) + r * VPAD + SEGLEN];
  } else {
    int row = LTOT + (r - (NSEG - 1));
    ao[(size_t)row * HID + c] = 0;
  }
}

extern "C" void kernel_launch(void* const* d_in, const int* in_sizes, int n_in,
                              void* d_out, int out_size, void* d_ws, size_t ws_size,
                              hipStream_t stream) {
  const float* x  = (const float*)d_in[0];
  const float* wq = (const float*)d_in[1];
  const float* bq = (const float*)d_in[2];
  const float* wk = (const float*)d_in[3];
  const float* bk = (const float*)d_in[4];
  const float* wv = (const float*)d_in[5];
  const float* bv = (const float*)d_in[6];
  const float* wo = (const float*)d_in[7];
  const float* bo = (const float*)d_in[8];
  float* out = (float*)d_out;

  u16* ws = (u16*)d_ws;
  u16* xb   = ws;                    // SEQ*HID
  u16* wqb  = xb  + (size_t)SEQ * HID;
  u16* wkb  = wqb + (size_t)HID * HID;
  u16* wvb  = wkb + (size_t)HID * HID;
  u16* wob  = wvb + (size_t)HID * HID;
  u16* qb   = wob + (size_t)HID * HID;
  u16* kbuf = qb  + (size_t)SEQ * HID;
  u16* vT   = kbuf + (size_t)SEQ * HID;  // [HID][NSEG*VPAD]
  u16* aob  = vT  + (size_t)HID * (NSEG * VPAD);

  cvt_all_kernel<<<7168, 256, 0, stream>>>(x, wq, wk, wv, wo, ws);

  qkv_gemm_kernel<<<dim3(SEQ / 128, 24), 512, 0, stream>>>(
      xb, wqb, wkb, wvb, bq, bk, bv, qb, kbuf, vT);

  attn_kernel<<<dim3(6, NSEG, HEADS), 256, 0, stream>>>(qb, kbuf, vT, aob);

  fixup_kernel<<<32 * 1024 / 256, 256, 0, stream>>>(vT, aob);

  out_gemm_kernel<<<dim3(SEQ / 128, HID / 64), 512, 0, stream>>>(aob, wob, bo, out);

  (void)in_sizes; (void)n_in; (void)out_size; (void)ws_size;
}